// Round 1
// baseline (248.632 us; speedup 1.0000x reference)
//
#include <hip/hip_runtime.h>
#include <hip/hip_bf16.h>

#define N_EMBD 1024
#define NW     110592
#define NCHUNK 96

typedef __attribute__((ext_vector_type(8)))  short          short8;
typedef __attribute__((ext_vector_type(16))) float          floatx16;
typedef __attribute__((ext_vector_type(4)))  float          float4v;
typedef __attribute__((ext_vector_type(4)))  unsigned short ushort4v;

// chunk sizes: 48 x 1024, 24 x 2048, 24 x 512
__device__ __forceinline__ void chunk_info(int l, int& S, int& off) {
  if (l < 48)      { S = 1024; off = l * 1024; }
  else if (l < 72) { S = 2048; off = 49152 + (l - 48) * 2048; }
  else             { S = 512;  off = 98304 + (l - 72) * 512; }
}

// fp32 -> bf16 with round-to-nearest-even
__device__ __forceinline__ unsigned short f2bf(float f) {
  unsigned u = __float_as_uint(f);
  u += 0x7fffu + ((u >> 16) & 1u);
  return (unsigned short)(u >> 16);
}

__device__ __forceinline__ float bf2f(unsigned short u) {
  return __uint_as_float(((unsigned)u) << 16);
}

// ---------------- encoder: reps[l*32+b][d] = sum_k x[b, off_l+k] * W_enc[l][k][d]
// grid (96, 8), block 256 (4 waves). wave tile: 32 rows x 32 cols, K-step 16.
__global__ __launch_bounds__(256) void enc_kernel(
    const float* __restrict__ P, const float* __restrict__ We,
    unsigned short* __restrict__ reps) {
  int l = blockIdx.x;
  int S, off; chunk_info(l, S, off);
  int tid = threadIdx.x;
  int wave = tid >> 6, lane = tid & 63;
  int lo = lane & 31, hi = lane >> 5;
  int col = blockIdx.y * 128 + wave * 32 + lo;          // 0..1023
  const float* Arow = P  + (size_t)lo * NW + off;       // batch row = lo
  const float* Bcol = We + (size_t)l * (2048 * N_EMBD) + col;

  floatx16 acc;
#pragma unroll
  for (int i = 0; i < 16; ++i) acc[i] = 0.f;

#pragma unroll 2
  for (int k0 = 0; k0 < S; k0 += 16) {
    int ka = k0 + hi * 8;
    // A fragment: row lo, k = ka..ka+7 (contiguous fp32)
    float4v a0 = *(const float4v*)(Arow + ka);
    float4v a1 = *(const float4v*)(Arow + ka + 4);
    // B fragment: col fixed, k = ka..ka+7 (stride N_EMBD)
    const float* bp = Bcol + (size_t)ka * N_EMBD;
    float bv[8];
#pragma unroll
    for (int j = 0; j < 8; ++j) bv[j] = bp[j * N_EMBD];

    short8 af, bf;
#pragma unroll
    for (int j = 0; j < 4; ++j) {
      af[j]     = (short)f2bf(a0[j]);
      af[j + 4] = (short)f2bf(a1[j]);
    }
#pragma unroll
    for (int j = 0; j < 8; ++j) bf[j] = (short)f2bf(bv[j]);

    acc = __builtin_amdgcn_mfma_f32_32x32x16_bf16(af, bf, acc, 0, 0, 0);
  }

  // C/D layout (verified m74/m101): col = lane&31, row = (reg&3)+8*(reg>>2)+4*(lane>>5)
  unsigned short* outp = reps + (size_t)(l * 32) * N_EMBD + col;
#pragma unroll
  for (int r = 0; r < 16; ++r) {
    int row = (r & 3) + 8 * (r >> 2) + 4 * hi;
    outp[(size_t)row * N_EMBD] = f2bf(acc[r]);
  }
}

// ---------------- layernorm over each of the 3072 rows of reps, write bf16
// grid 768, block 256 = 4 waves, one wave per row.
__global__ __launch_bounds__(256) void ln_kernel(
    const unsigned short* __restrict__ reps, const float* __restrict__ gamma,
    const float* __restrict__ beta, unsigned short* __restrict__ out) {
  int row  = blockIdx.x * 4 + (threadIdx.x >> 6);
  int lane = threadIdx.x & 63;
  const unsigned short* rp = reps + (size_t)row * N_EMBD;

  float x[16];
#pragma unroll
  for (int j = 0; j < 4; ++j) {
    ushort4v v = *(const ushort4v*)(rp + j * 256 + lane * 4);
#pragma unroll
    for (int t = 0; t < 4; ++t) x[j * 4 + t] = bf2f(v[t]);
  }
  float s = 0.f, s2 = 0.f;
#pragma unroll
  for (int i = 0; i < 16; ++i) { s += x[i]; s2 += x[i] * x[i]; }
#pragma unroll
  for (int m = 1; m < 64; m <<= 1) {
    s  += __shfl_xor(s,  m, 64);
    s2 += __shfl_xor(s2, m, 64);
  }
  float mu  = s * (1.f / 1024.f);
  float var = s2 * (1.f / 1024.f) - mu * mu;
  float rs  = rsqrtf(var + 1e-5f);

  unsigned short* op = out + (size_t)row * N_EMBD;
#pragma unroll
  for (int j = 0; j < 4; ++j) {
    int d = j * 256 + lane * 4;
    float4v g  = *(const float4v*)(gamma + d);
    float4v bt = *(const float4v*)(beta + d);
    ushort4v o;
#pragma unroll
    for (int t = 0; t < 4; ++t)
      o[t] = f2bf((x[j * 4 + t] - mu) * rs * g[t] + bt[t]);
    *(ushort4v*)(op + d) = o;
  }
}

// ---------------- decoder: out[b][off_l + j] = sum_d rln[l*32+b][d] * W_dec[l][d][j]
// grid (96, 16), block 256 (4 waves); blocks with j-tile >= S_l exit early.
__global__ __launch_bounds__(256) void dec_kernel(
    const unsigned short* __restrict__ rln, const float* __restrict__ Wd,
    float* __restrict__ out) {
  int l = blockIdx.x;
  int S, off; chunk_info(l, S, off);
  int n0 = blockIdx.y * 128;
  if (n0 >= S) return;
  int tid = threadIdx.x;
  int wave = tid >> 6, lane = tid & 63;
  int lo = lane & 31, hi = lane >> 5;
  int col = n0 + wave * 32 + lo;                        // 0..S-1
  const unsigned short* Arow = rln + (size_t)(l * 32 + lo) * N_EMBD;
  const float* Bcol = Wd + (size_t)l * (N_EMBD * 2048) + col;

  floatx16 acc;
#pragma unroll
  for (int i = 0; i < 16; ++i) acc[i] = 0.f;

#pragma unroll 2
  for (int k0 = 0; k0 < N_EMBD; k0 += 16) {
    int ka = k0 + hi * 8;
    short8 af = *(const short8*)(Arow + ka);            // bf16, already converted
    const float* bp = Bcol + (size_t)ka * 2048;
    float bv[8];
#pragma unroll
    for (int j = 0; j < 8; ++j) bv[j] = bp[j * 2048];
    short8 bf;
#pragma unroll
    for (int j = 0; j < 8; ++j) bf[j] = (short)f2bf(bv[j]);
    acc = __builtin_amdgcn_mfma_f32_32x32x16_bf16(af, bf, acc, 0, 0, 0);
  }

#pragma unroll
  for (int r = 0; r < 16; ++r) {
    int row = (r & 3) + 8 * (r >> 2) + 4 * hi;          // batch index
    out[(size_t)row * NW + off + col] = acc[r];
  }
}

extern "C" void kernel_launch(void* const* d_in, const int* in_sizes, int n_in,
                              void* d_out, int out_size, void* d_ws, size_t ws_size,
                              hipStream_t stream) {
  const float* P  = (const float*)d_in[0];
  const float* We = (const float*)d_in[1];
  const float* Wd = (const float*)d_in[2];
  const float* g  = (const float*)d_in[3];
  const float* bt = (const float*)d_in[4];
  float* out = (float*)d_out;

  unsigned short* reps = (unsigned short*)d_ws;                 // 96*32*1024 bf16 = 6.29 MB
  unsigned short* rln  = reps + (size_t)NCHUNK * 32 * N_EMBD;   // another 6.29 MB

  enc_kernel<<<dim3(NCHUNK, 8), 256, 0, stream>>>(P, We, reps);
  ln_kernel<<<768, 256, 0, stream>>>(reps, g, bt, rln);
  dec_kernel<<<dim3(NCHUNK, 16), 256, 0, stream>>>(rln, Wd, out);
}

// Round 2
// 206.871 us; speedup vs baseline: 1.2019x; 1.2019x over previous
//
#include <hip/hip_runtime.h>
#include <hip/hip_bf16.h>

#define N_EMBD 1024
#define NW     110592
#define NCHUNK 96

typedef __attribute__((ext_vector_type(8)))  short          short8;
typedef __attribute__((ext_vector_type(8)))  unsigned short ushort8;
typedef __attribute__((ext_vector_type(16))) float          floatx16;
typedef __attribute__((ext_vector_type(4)))  float          float4v;

// chunk sizes: 48 x 1024, 24 x 2048, 24 x 512
__device__ __forceinline__ void chunk_info(int l, int& S, int& off) {
  if (l < 48)      { S = 1024; off = l * 1024; }
  else if (l < 72) { S = 2048; off = 49152 + (l - 48) * 2048; }
  else             { S = 512;  off = 98304 + (l - 72) * 512; }
}

// heavy-first (LPT) chunk order: 24 x S=2048, then 48 x S=1024, then 24 x S=512
__device__ __forceinline__ int remap_chunk(int x) {
  return (x < 24) ? (48 + x) : (x < 72 ? x - 24 : x);
}

// fp32 -> bf16 round-to-nearest-even
__device__ __forceinline__ unsigned short f2bf(float f) {
  unsigned u = __float_as_uint(f);
  u += 0x7fffu + ((u >> 16) & 1u);
  return (unsigned short)(u >> 16);
}
__device__ __forceinline__ float bf2f(unsigned short u) {
  return __uint_as_float(((unsigned)u) << 16);
}

#define GLOAD_LDS16(g, l) \
  __builtin_amdgcn_global_load_lds((const __attribute__((address_space(1))) unsigned int*)(g), \
                                   (__attribute__((address_space(3))) unsigned int*)(l), 16, 0, 0)

// ---------------- transpose: xswz[kb][b][e] = bf16(P[b][kb*8+e]); kb = global k / 8
// 16B/lane writes fully coalesced; grid 1728 x 256.
__global__ __launch_bounds__(256) void xpose_kernel(
    const float* __restrict__ P, unsigned short* __restrict__ xswz) {
  int t = blockIdx.x * 256 + threadIdx.x;   // t < (NW/8)*32
  int b = t & 31, kb = t >> 5;
  const float* src = P + (size_t)b * NW + (size_t)kb * 8;
  float4v v0 = *(const float4v*)(src);
  float4v v1 = *(const float4v*)(src + 4);
  ushort8 o;
#pragma unroll
  for (int j = 0; j < 4; ++j) { o[j] = f2bf(v0[j]); o[j + 4] = f2bf(v1[j]); }
  *(ushort8*)(xswz + (size_t)t * 8) = o;
}

// ---------------- encoder: reps[l*32+b][d] = sum_k x[b,off+k] * We[l][k][d]
// grid (96, 8), 256 thr (4 waves). 32x128 tile, K-step 32, LDS-staged B (dbuf).
__global__ __launch_bounds__(256) void enc_kernel(
    const unsigned short* __restrict__ xswz, const float* __restrict__ We,
    unsigned short* __restrict__ reps) {
  __shared__ float Bt[2][32][128];
  int l = remap_chunk(blockIdx.x);
  int S, off; chunk_info(l, S, off);
  int tid = threadIdx.x, w = tid >> 6, lane = tid & 63;
  int lo = lane & 31, hi = lane >> 5;
  int c0 = blockIdx.y * 128;
  // staging source: wave w covers rows w*8..w*8+7 (2 rows / 1KB per instr)
  const float* Wb = We + (size_t)l * (2048 * N_EMBD)
                  + (size_t)(w * 8 + hi) * N_EMBD + c0 + lo * 4;
  // A: blocked bf16, one dwordx4 per MFMA: addr = (off+ka)*32 + lo*8 elems
  const unsigned short* Ab = xswz + (size_t)off * 32 + lo * 8;

  floatx16 acc = {};
  int cur = 0;

  // prologue stage k0=0 into buf 0
#pragma unroll
  for (int q = 0; q < 4; ++q)
    GLOAD_LDS16(Wb + (size_t)(q * 2) * N_EMBD, &Bt[0][w * 8 + q * 2][0]);
  __syncthreads();

  for (int k0 = 0; k0 < S; k0 += 32) {
    if (k0 + 32 < S) {
      const float* s = Wb + (size_t)(k0 + 32) * N_EMBD;
#pragma unroll
      for (int q = 0; q < 4; ++q)
        GLOAD_LDS16(s + (size_t)(q * 2) * N_EMBD, &Bt[cur ^ 1][w * 8 + q * 2][0]);
    }
#pragma unroll
    for (int ks = 0; ks < 2; ++ks) {
      int ka = k0 + ks * 16 + hi * 8;
      short8 af = *(const short8*)(Ab + (size_t)ka * 32);
      int kl = ks * 16 + hi * 8;
      short8 bf;
#pragma unroll
      for (int j = 0; j < 8; ++j) bf[j] = (short)f2bf(Bt[cur][kl + j][w * 32 + lo]);
      acc = __builtin_amdgcn_mfma_f32_32x32x16_bf16(af, bf, acc, 0, 0, 0);
    }
    __syncthreads();
    cur ^= 1;
  }

  // C/D: col = lane&31, row = (reg&3)+8*(reg>>2)+4*(lane>>5)
  unsigned short* outp = reps + (size_t)(l * 32) * N_EMBD + c0 + w * 32 + lo;
#pragma unroll
  for (int r = 0; r < 16; ++r) {
    int row = (r & 3) + 8 * (r >> 2) + 4 * hi;
    outp[(size_t)row * N_EMBD] = f2bf(acc[r]);
  }
}

// ---------------- layernorm rows of reps -> rlnswz in blocked layout
// rlnswz elem addr = l*32768 + (d>>3)*256 + b*8 + (d&7). grid 768 x 256, wave/row.
__global__ __launch_bounds__(256) void ln_kernel(
    const unsigned short* __restrict__ reps, const float* __restrict__ gamma,
    const float* __restrict__ beta, unsigned short* __restrict__ rlnswz) {
  int row  = blockIdx.x * 4 + (threadIdx.x >> 6);
  int lane = threadIdx.x & 63;
  int l = row >> 5, b = row & 31;
  const unsigned short* rp = reps + (size_t)row * N_EMBD;

  float x[16];
#pragma unroll
  for (int j = 0; j < 2; ++j) {
    int g = j * 64 + lane;
    ushort8 v = *(const ushort8*)(rp + g * 8);
#pragma unroll
    for (int t = 0; t < 8; ++t) x[j * 8 + t] = bf2f(v[t]);
  }
  float s = 0.f, s2 = 0.f;
#pragma unroll
  for (int i = 0; i < 16; ++i) { s += x[i]; s2 += x[i] * x[i]; }
#pragma unroll
  for (int m = 1; m < 64; m <<= 1) {
    s  += __shfl_xor(s,  m, 64);
    s2 += __shfl_xor(s2, m, 64);
  }
  float mu  = s * (1.f / 1024.f);
  float var = s2 * (1.f / 1024.f) - mu * mu;
  float rs  = rsqrtf(var + 1e-5f);

  unsigned short* op = rlnswz + (size_t)l * 32768 + b * 8;
#pragma unroll
  for (int j = 0; j < 2; ++j) {
    int g = j * 64 + lane;
    float4v g0 = *(const float4v*)(gamma + g * 8);
    float4v g1 = *(const float4v*)(gamma + g * 8 + 4);
    float4v b0 = *(const float4v*)(beta + g * 8);
    float4v b1 = *(const float4v*)(beta + g * 8 + 4);
    ushort8 o;
#pragma unroll
    for (int t = 0; t < 4; ++t) {
      o[t]     = f2bf((x[j * 8 + t]     - mu) * rs * g0[t] + b0[t]);
      o[t + 4] = f2bf((x[j * 8 + 4 + t] - mu) * rs * g1[t] + b1[t]);
    }
    *(ushort8*)(op + (size_t)g * 256) = o;
  }
}

// ---------------- decoder: out[b][off+j] = sum_d rln[l*32+b][d] * Wd[l][d][j]
// grid (96, 16), 256 thr; blocks with c0 >= S exit. Same structure as enc.
__global__ __launch_bounds__(256) void dec_kernel(
    const unsigned short* __restrict__ rlnswz, const float* __restrict__ Wd,
    float* __restrict__ out) {
  __shared__ float Bt[2][32][128];
  int l = remap_chunk(blockIdx.x);
  int S, off; chunk_info(l, S, off);
  int c0 = blockIdx.y * 128;
  if (c0 >= S) return;
  int tid = threadIdx.x, w = tid >> 6, lane = tid & 63;
  int lo = lane & 31, hi = lane >> 5;
  const float* Wb = Wd + (size_t)l * (N_EMBD * 2048)
                  + (size_t)(w * 8 + hi) * 2048 + c0 + lo * 4;
  const unsigned short* Ab = rlnswz + (size_t)l * 32768 + lo * 8;

  floatx16 acc = {};
  int cur = 0;

#pragma unroll
  for (int q = 0; q < 4; ++q)
    GLOAD_LDS16(Wb + (size_t)(q * 2) * 2048, &Bt[0][w * 8 + q * 2][0]);
  __syncthreads();

  for (int k0 = 0; k0 < N_EMBD; k0 += 32) {
    if (k0 + 32 < N_EMBD) {
      const float* s = Wb + (size_t)(k0 + 32) * 2048;
#pragma unroll
      for (int q = 0; q < 4; ++q)
        GLOAD_LDS16(s + (size_t)(q * 2) * 2048, &Bt[cur ^ 1][w * 8 + q * 2][0]);
    }
#pragma unroll
    for (int ks = 0; ks < 2; ++ks) {
      int ka = k0 + ks * 16 + hi * 8;
      short8 af = *(const short8*)(Ab + (size_t)ka * 32);
      int kl = ks * 16 + hi * 8;
      short8 bf;
#pragma unroll
      for (int j = 0; j < 8; ++j) bf[j] = (short)f2bf(Bt[cur][kl + j][w * 32 + lo]);
      acc = __builtin_amdgcn_mfma_f32_32x32x16_bf16(af, bf, acc, 0, 0, 0);
    }
    __syncthreads();
    cur ^= 1;
  }

#pragma unroll
  for (int r = 0; r < 16; ++r) {
    int row = (r & 3) + 8 * (r >> 2) + 4 * hi;  // batch index
    out[(size_t)row * NW + off + c0 + w * 32 + lo] = acc[r];
  }
}

extern "C" void kernel_launch(void* const* d_in, const int* in_sizes, int n_in,
                              void* d_out, int out_size, void* d_ws, size_t ws_size,
                              hipStream_t stream) {
  const float* P  = (const float*)d_in[0];
  const float* We = (const float*)d_in[1];
  const float* Wd = (const float*)d_in[2];
  const float* g  = (const float*)d_in[3];
  const float* bt = (const float*)d_in[4];
  float* out = (float*)d_out;

  unsigned short* xswz   = (unsigned short*)d_ws;                    // NW*32 bf16 = 7.08 MB
  unsigned short* reps   = xswz + (size_t)NW * 32;                   // 6.29 MB
  unsigned short* rlnswz = reps + (size_t)NCHUNK * 32 * N_EMBD;      // 6.29 MB

  xpose_kernel<<<(NW / 8) * 32 / 256, 256, 0, stream>>>(P, xswz);
  enc_kernel<<<dim3(NCHUNK, 8), 256, 0, stream>>>(xswz, We, reps);
  ln_kernel<<<768, 256, 0, stream>>>(reps, g, bt, rlnswz);
  dec_kernel<<<dim3(NCHUNK, 16), 256, 0, stream>>>(rlnswz, Wd, out);
}